// Round 4
// baseline (245.356 us; speedup 1.0000x reference)
//
#include <hip/hip_runtime.h>
#include <utility>

// EquivariantProductBasisBlock (MACE-style) for gfx950 — round 15.
// R14 counters killed the VGPR-cliff theory: VGPR=84, LDS=40KB, but
// VALUBusy=23%, Occupancy=22%, HBM 6% -> LATENCY-bound. Phase A issues
// ~80 dependent small global loads/thread (18 nf + 9 w2 + 51 w3) at point
// of use, ~250cy L2 latency each, with only 4 waves/SIMD resident (grid
// 1024 = 4 blocks/CU; LDS 40KB also caps 4). 4-deep overlap over a
// serialized load->use chain ~= 25% util = exactly what VALUBusy shows.
// R15: 1 channel/thread (scalar). Total VALU-issue unchanged (pk_fma not
// 2x on gfx950), but grid doubles to 2048 blocks = 8 blocks/CU; LDS 20KB
// (Bsh 4K + Red 16K) fits 8; launch_bounds(256,8) caps VGPR at 64 (scalar
// phase A needs ~55). nf loads 18 scalar -> 2 dwordx4 + 1 dword (align-4
// vec). Predict: VGPR<=64, Occ 22->~45%, VALUBusy 23->~48%, kernel
// 45.7 -> ~24us, dur ~88.

#define NN 4096
#define NC 128
#define NE 10

typedef float f4u __attribute__((ext_vector_type(4), aligned(4)));

// ---------------------------- static_for ---------------------------------------
template<typename F, int... Is>
__device__ __forceinline__ void sfor_impl(F&& f, std::integer_sequence<int, Is...>) {
  (f(std::integral_constant<int, Is>{}), ...);
}
template<int N, typename F>
__device__ __forceinline__ void sfor(F&& f) {
  sfor_impl((F&&)f, std::make_integer_sequence<int, N>{});
}

// ---------------------------- CG metadata (constexpr) --------------------------
constexpr int T_L1c[19]  = {0,0,0,1,1,1,1,1,1,1,2,2,2,2,2,2,2,2,3};
constexpr int T_L2c[19]  = {0,1,2,0,1,1,1,2,2,2,0,1,1,1,2,2,2,2,2};
constexpr int T_L3c[19]  = {0,1,2,1,0,1,2,1,2,3,2,1,2,3,0,1,2,3,1};
constexpr int T_OFFc[19] = {0,1,10,35,44,53,80,125,170,245,350,375,420,495,600,625,700,825,1000};
constexpr int AOFFc[3]   = {0,1,4};

constexpr int P2U_L1c[7]  = {0,0,1,1,1,2,2};
constexpr int P2U_L2c[7]  = {0,1,1,1,2,2,2};
constexpr int P2U_LOc[7]  = {0,1,0,1,1,0,1};
constexpr int P2U_TBLc[7] = {0,1,4,5,7,14,15};
constexpr int P2U_WAc[7]  = {0,1,3,4,5,7,8};
constexpr int P2U_WBc[7]  = {-1,2,-1,-1,6,-1,-1};

constexpr int K_L1c[18]  = {0,0,0,1,1,1,1,1,1,1,2,2,2,2,2,2,2,2};
constexpr int K_L2c[18]  = {0,1,2,0,1,1,1,2,2,2,0,1,1,1,2,2,2,2};
constexpr int K_L12c[18] = {0,1,2,1,0,1,2,1,2,3,2,1,2,3,0,1,2,3};

constexpr int   TT_CANONc[18] = {0,1,2,1,4,5,6,7,8,9,2,7,8,9,14,15,16,17};
constexpr float TT_SGNc[18]   = {1,1,1,1,1,1,1,1,1,1,1,1,-1,1,1,1,1,1};
constexpr int CANONc[13] = {0,1,2,4,5,6,7,8,9,14,15,16,17};
constexpr int CONS2c[13] = {-1,3,10,-1,-1,-1,11,12,13,-1,-1,-1,-1};

constexpr int P3_STARTc[19] = {0,2,6,9,13,15,19,22,26,29,30,33,37,40,41,43,47,50,51};
constexpr int P3_L3c[51] = {
  0,1,  0,1,1,2,  1,2,2,  0,1,1,2,  0,1,  0,1,1,2,  1,2,2,  0,1,1,2,  1,2,2,
  2,  1,2,2,  0,1,1,2,  1,2,2,  2,  0,1,  0,1,1,2,  1,2,2,  2 };
constexpr int P3_LOc[51] = {
  0,1,  1,0,1,1,  1,0,1,  1,0,1,1,  0,1,  1,0,1,1,  1,0,1,  1,0,1,1,  1,0,1,
  1,  1,0,1,  1,0,1,1,  1,0,1,  1,  0,1,  1,0,1,1,  1,0,1,  1 };
constexpr int P3_TBLc[51] = {
  0,1,  3,4,5,7,  11,14,15,  3,4,5,7,  0,1,  3,4,5,7,  11,14,15,  3,4,5,7,
  11,14,15,  18,  11,14,15,  3,4,5,7,  11,14,15,  18,  0,1,  3,4,5,7,
  11,14,15,  18 };

// ---------------------------- constexpr CG computation -------------------------
constexpr double cfact(int n) { double r = 1.0; for (int i = 2; i <= n; ++i) r *= i; return r; }
constexpr double csqrt(double x) {
  if (x <= 0.0) return 0.0;
  double r = x > 1.0 ? x : 1.0;
  for (int i = 0; i < 64; ++i) r = 0.5 * (r + x / r);
  return r;
}
constexpr double su2cg(int j1, int m1, int j2, int m2, int j3, int m3) {
  if (m3 != m1 + m2) return 0.0;
  int vmin = -j1 + j2 + m3; if (-j1 + m1 > vmin) vmin = -j1 + m1; if (vmin < 0) vmin = 0;
  int vmax = j2 + j3 + m1; if (j3 - j1 + j2 < vmax) vmax = j3 - j1 + j2; if (j3 + m3 < vmax) vmax = j3 + m3;
  double C = csqrt((2.0 * j3 + 1.0)
                   * cfact(j3 + j1 - j2) * cfact(j3 - j1 + j2) * cfact(j1 + j2 - j3)
                   * cfact(j3 + m3) * cfact(j3 - m3)
                   / (cfact(j1 + j2 + j3 + 1) * cfact(j1 - m1) * cfact(j1 + m1)
                      * cfact(j2 - m2) * cfact(j2 + m2)));
  double S = 0.0;
  for (int v = vmin; v <= vmax; ++v) {
    double sgn = ((v + j2 + m2) & 1) ? -1.0 : 1.0;
    S += sgn * cfact(j2 + j3 + m1 - v) * cfact(j1 - m1 + v)
         / (cfact(v) * cfact(j3 - j1 + j2 - v) * cfact(j3 + m3 - v) * cfact(v + j1 - j2 - m3));
  }
  return C * S;
}

struct Cx { double re, im; };
constexpr Cx cxmul(Cx a, Cx b) { return Cx{a.re * b.re - a.im * b.im, a.re * b.im + a.im * b.re}; }
struct Row { int cnt; int col[2]; Cx v[2]; };

constexpr Row c2r_row(int l, int r) {
  Row out{0, {0, 0}, {{0, 0}, {0, 0}}};
  constexpr double is2 = 0.70710678118654752440;
  const int m = r - l;
  if (m < 0) {
    out.cnt = 2;
    out.col[0] = l - m; out.v[0] = Cx{is2, 0.0};
    out.col[1] = l + m; out.v[1] = Cx{0.0, -is2};
  } else if (m == 0) {
    out.cnt = 1; out.col[0] = l; out.v[0] = Cx{1.0, 0.0};
  } else {
    const double sgn = (m & 1) ? -1.0 : 1.0;
    out.cnt = 2;
    out.col[0] = l + m; out.v[0] = Cx{sgn * is2, 0.0};
    out.col[1] = l - m; out.v[1] = Cx{0.0, sgn * is2};
  }
  const int ph = l & 3;
  for (int a = 0; a < out.cnt; ++a) {
    Cx v = out.v[a];
    out.v[a] = (ph == 0) ? v
             : (ph == 1) ? Cx{v.im, -v.re}
             : (ph == 2) ? Cx{-v.re, -v.im}
                         : Cx{-v.im, v.re};
  }
  return out;
}

struct CGAll { float v[1105]; };
constexpr CGAll make_cg() {
  CGAll R{};
  for (int t = 0; t < 19; ++t) {
    const int l1 = T_L1c[t], l2 = T_L2c[t], l3 = T_L3c[t], off = T_OFFc[t];
    const int d1 = 2 * l1 + 1, d2 = 2 * l2 + 1, d3 = 2 * l3 + 1;
    double tmp[175] = {};
    for (int i = 0; i < d1; ++i) {
      const int m1 = i - l1;
      const Row r1 = c2r_row(l1, i);
      for (int k = 0; k < d2; ++k) {
        const int m2 = k - l2, m3 = m1 + m2;
        if (m3 < -l3 || m3 > l3) continue;
        const double cc = su2cg(l1, m1, l2, m2, l3, m3);
        if (cc == 0.0) continue;
        const Row r2 = c2r_row(l2, k);
        const Row r3 = c2r_row(l3, m3 + l3);
        for (int a = 0; a < r1.cnt; ++a)
          for (int b = 0; b < r2.cnt; ++b) {
            const Cx q12 = cxmul(r1.v[a], r2.v[b]);
            for (int cdx = 0; cdx < r3.cnt; ++cdx) {
              const double re = q12.re * r3.v[cdx].re + q12.im * r3.v[cdx].im;
              tmp[(r1.col[a] * d2 + r2.col[b]) * d3 + r3.col[cdx]] += re * cc;
            }
          }
      }
    }
    const int sz = d1 * d2 * d3;
    for (int e = 0; e < sz; ++e) R.v[off + e] = (float)tmp[e];
  }
  return R;
}
constexpr CGAll CG_ALL = make_cg();

constexpr bool check_cg_sym() {
  for (int t = 0; t < 18; ++t) {
    const int tc = TT_CANONc[t];
    if (tc == t) continue;
    const int l1 = K_L1c[t], l2 = K_L2c[t], l12 = K_L12c[t];
    const int d1 = 2*l1+1, d2 = 2*l2+1, d12 = 2*l12+1;
    for (int i = 0; i < d1; ++i)
      for (int j = 0; j < d2; ++j)
        for (int k = 0; k < d12; ++k) {
          float a = CG_ALL.v[T_OFFc[t]  + (i*d2 + j)*d12 + k];
          float b = TT_SGNc[t] * CG_ALL.v[T_OFFc[tc] + (j*d1 + i)*d12 + k];
          float d = a - b; if (d < 0) d = -d;
          if (d > 1e-5f) return false;
        }
  }
  return true;
}
static_assert(check_cg_sym(), "CG exchange symmetry violated");

// ============================ fused basis + linear kernel ======================
// Block = 2 nodes x 256 threads (1 channel/thread), 2048 blocks = 8/CU.
// Phase A: t = node(t>>7) x channel(t&127); B (4 floats) -> Bsh 4KB.
// Phase B: t = (q = f-quad 0..31, wv = 32-ch chunk 0..3, node = t>>7);
// partials -> 16KB Red; 4-way tree-reduce + coalesced float4 store.
__global__ __launch_bounds__(256, 8) void epb_fused(
    const float*  __restrict__ nf,      // [N, C, 9]
    const float*  __restrict__ w1,      // [E, 2, C]
    const float*  __restrict__ w2,      // [E, 9, C]
    const float*  __restrict__ w3,      // [E, 51, C]
    const float4* __restrict__ lw0_4,   // [C, F/4]
    const float4* __restrict__ lw1_4,   // [C, F/4]
    const int*    __restrict__ species, // [N]
    float* __restrict__ out)            // [N, F, 4]
{
  __shared__ float4 Bsh[2 * NC];        //  4 KB  [node][channel] (m0..m3)
  __shared__ float4 Red[8 * NC];        // 16 KB  [node*4+f_local][chunk*32+q]

  const int t  = threadIdx.x;
  const int nb = blockIdx.x * 2;

  // ---------------- phase A: basis (scalar, 1 ch/thread) -------------------
  {
    const int nl = t >> 7;               // node 0/1 (wave-uniform)
    const int c  = t & 127;              // channel
    const int n  = nb + nl;
    const int s  = species[n];

    const float* ap = nf + ((size_t)n * NC + c) * 9;
    float A[9];
    {
      const f4u v0 = *reinterpret_cast<const f4u*>(ap);
      const f4u v1 = *reinterpret_cast<const f4u*>(ap + 4);
      sfor<4>([&](auto I) { A[I.value] = v0[I.value]; A[I.value + 4] = v1[I.value]; });
      A[8] = ap[8];
    }

    const float* w1p = w1 + (size_t)s * 2  * NC + c;
    const float* w2p = w2 + (size_t)s * 9  * NC + c;
    const float* w3p = w3 + (size_t)s * 51 * NC + c;

    float B[4];
    {
      const float wa = w1p[0], wb = w1p[NC];
      B[0] = wa * A[0];
      B[1] = wb * A[1];
      B[2] = wb * A[2];
      B[3] = wb * A[3];
    }

    sfor<7>([&](auto P) {
      constexpr int p  = P.value;
      constexpr int l1 = P2U_L1c[p], l2 = P2U_L2c[p], lo = P2U_LOc[p];
      constexpr int d1 = 2*l1+1, d2 = 2*l2+1, dl = 2*lo+1;
      constexpr int off = T_OFFc[P2U_TBLc[p]];
      float w = w2p[P2U_WAc[p] * NC];
      if constexpr (P2U_WBc[p] >= 0) w += w2p[P2U_WBc[p] * NC];
      sfor<dl>([&](auto Kk) {
        constexpr int k = Kk.value;
        float v = 0.f;
        sfor<d1>([&](auto I) {
          sfor<d2>([&](auto J) {
            constexpr float cgc = CG_ALL.v[off + (I.value * d2 + J.value) * dl + k];
            if constexpr (cgc != 0.0f) {
              constexpr int ia = AOFFc[l1] + I.value, ja = AOFFc[l2] + J.value;
              constexpr int x = ia < ja ? ia : ja, y = ia < ja ? ja : ia;
              v = fmaf(cgc, A[x] * A[y], v);
            }
          });
        });
        B[lo + k] = fmaf(w, v, B[lo + k]);
      });
    });

    sfor<13>([&](auto CI) {
      constexpr int tk  = CANONc[CI.value];
      constexpr int l1  = K_L1c[tk], l2 = K_L2c[tk], l12 = K_L12c[tk];
      constexpr int d1  = 2*l1+1, d2 = 2*l2+1, d12 = 2*l12+1;
      constexpr int off = T_OFFc[tk];
      float tt[d12];
      sfor<d12>([&](auto Kk) {
        constexpr int k = Kk.value;
        float v = 0.f;
        sfor<d1>([&](auto I) {
          sfor<d2>([&](auto J) {
            constexpr float cgc = CG_ALL.v[off + (I.value * d2 + J.value) * d12 + k];
            if constexpr (cgc != 0.0f) {
              constexpr int ia = AOFFc[l1] + I.value, ja = AOFFc[l2] + J.value;
              constexpr int x = ia < ja ? ia : ja, y = ia < ja ? ja : ia;
              v = fmaf(cgc, A[x] * A[y], v);
            }
          });
        });
        tt[k] = v;
      });

      auto consume = [&](auto TK, auto SG) {
        constexpr int tkey = TK.value;
        constexpr float sgn = (float)SG.value;
        constexpr int pcnt = P3_STARTc[tkey + 1] - P3_STARTc[tkey];
        sfor<pcnt>([&](auto PP) {
          constexpr int p  = P3_STARTc[tkey] + PP.value;
          constexpr int l3 = P3_L3c[p], lo = P3_LOc[p];
          constexpr int d3 = 2*l3+1, dl = 2*lo+1;
          constexpr int off2 = T_OFFc[P3_TBLc[p]];
          const float w = w3p[p * NC];
          sfor<dl>([&](auto M) {
            float v = 0.f;
            sfor<d12>([&](auto Kk) {
              sfor<d3>([&](auto J) {
                constexpr float cgc = sgn * CG_ALL.v[off2 + (Kk.value * d3 + J.value) * dl + M.value];
                if constexpr (cgc != 0.0f)
                  v = fmaf(cgc, tt[Kk.value] * A[AOFFc[l3] + J.value], v);
              });
            });
            B[lo + M.value] = fmaf(w, v, B[lo + M.value]);
          });
        });
      };
      consume(std::integral_constant<int, tk>{}, std::integral_constant<int, 1>{});
      constexpr int td = CONS2c[CI.value];
      if constexpr (td >= 0)
        consume(std::integral_constant<int, td>{},
                std::integral_constant<int, (int)TT_SGNc[td]>{});
    });

    Bsh[nl * NC + c] = make_float4(B[0], B[1], B[2], B[3]);
  }
  __syncthreads();

  // ---------------- phase B: equivariant linear -----------------------------
  // thread -> (q = f-quad 0..31, wv = 32-ch chunk 0..3, nl2 = node 0/1)
  const int q   = t & 31;
  const int wv  = (t >> 5) & 3;
  const int nl2 = t >> 7;

  float4 acc[4] = {};                    // [f_local], comps in float4

  const float4* w0c = lw0_4 + (size_t)(wv * 32) * 32 + q;
  const float4* w1c = lw1_4 + (size_t)(wv * 32) * 32 + q;
  const float4* bp  = &Bsh[nl2 * NC + wv * 32];

  #pragma unroll 4
  for (int i = 0; i < 32; ++i) {
    const float4 wa = w0c[i * 32];       // 32 consecutive float4/half-wave -> coalesced
    const float4 wb = w1c[i * 32];
    const float4 b  = bp[i];             // 2 uniform addrs/wave -> broadcast
    acc[0].x = fmaf(b.x, wa.x, acc[0].x); acc[0].y = fmaf(b.y, wb.x, acc[0].y);
    acc[0].z = fmaf(b.z, wb.x, acc[0].z); acc[0].w = fmaf(b.w, wb.x, acc[0].w);
    acc[1].x = fmaf(b.x, wa.y, acc[1].x); acc[1].y = fmaf(b.y, wb.y, acc[1].y);
    acc[1].z = fmaf(b.z, wb.y, acc[1].z); acc[1].w = fmaf(b.w, wb.y, acc[1].w);
    acc[2].x = fmaf(b.x, wa.z, acc[2].x); acc[2].y = fmaf(b.y, wb.z, acc[2].y);
    acc[2].z = fmaf(b.z, wb.z, acc[2].z); acc[2].w = fmaf(b.w, wb.z, acc[2].w);
    acc[3].x = fmaf(b.x, wa.w, acc[3].x); acc[3].y = fmaf(b.y, wb.w, acc[3].y);
    acc[3].z = fmaf(b.z, wb.w, acc[3].z); acc[3].w = fmaf(b.w, wb.w, acc[3].w);
  }

  // partials: lanes of each write instr cover 64 consecutive float4 -> 1KB
  // contiguous, conflict-free.
  sfor<4>([&](auto F_) {
    Red[(nl2 * 4 + F_.value) * NC + wv * 32 + q] = acc[F_.value];
  });
  __syncthreads();

  // 4-way tree reduce + scale + coalesced store (1 float4 output per thread)
  const float s4 = 0.08838834764831845f;  // 1/sqrt(128)
  float4* o4 = reinterpret_cast<float4*>(out);
  {
    const int n   = t >> 7;               // node in block
    const int rem = t & 127;              // feature index
    const int row = (n * 4 + (rem & 3)) * NC + (rem >> 2);
    const float4 r0 = Red[row];
    const float4 r1 = Red[row + 32];
    const float4 r2 = Red[row + 64];
    const float4 r3 = Red[row + 96];
    o4[(size_t)(nb + n) * NC + rem] = make_float4(
        ((r0.x + r1.x) + (r2.x + r3.x)) * s4,
        ((r0.y + r1.y) + (r2.y + r3.y)) * s4,
        ((r0.z + r1.z) + (r2.z + r3.z)) * s4,
        ((r0.w + r1.w) + (r2.w + r3.w)) * s4);
  }
}

// ------------------------------- launcher --------------------------------------
extern "C" void kernel_launch(void* const* d_in, const int* in_sizes, int n_in,
                              void* d_out, int out_size, void* d_ws, size_t ws_size,
                              hipStream_t stream) {
  const float* nf  = (const float*)d_in[0];
  const float* w1  = (const float*)d_in[1];
  const float* w2  = (const float*)d_in[2];
  const float* w3  = (const float*)d_in[3];
  const float* lw0 = (const float*)d_in[4];
  const float* lw1 = (const float*)d_in[5];
  const int*   spc = (const int*)  d_in[6];
  float* out = (float*)d_out;
  (void)d_ws; (void)ws_size; (void)in_sizes; (void)n_in; (void)out_size;

  hipLaunchKernelGGL(epb_fused, dim3(NN / 2), dim3(256), 0, stream,
                     nf, w1, w2, w3, (const float4*)lw0, (const float4*)lw1,
                     spc, out);
}

// Round 5
// 111.483 us; speedup vs baseline: 2.2008x; 2.2008x over previous
//
#include <hip/hip_runtime.h>
#include <utility>

// EquivariantProductBasisBlock (MACE-style) for gfx950 — round 16.
// R15 post-mortem: launch_bounds(256,8) forced VGPR=32 -> massive scratch
// spills (FETCH 212MB, WRITE 324MB vs 19MB real input), kernel 181us.
// NEVER force occupancy below natural register footprint. R14 (84 VGPR,
// no spills) showed VALUBusy 23% = latency-bound: ~62 strided weight
// loads/thread (w1/w2/w3 are [paths][C], so a thread's 51 w3 values sit
// 512B apart = 51 latency events) at only 4 waves/SIMD.
// R16: (1) tiny per-launch transpose kernel packs w1|w2|w3 into
// wt[E][C][64] in d_ws -> each thread's weight stream is 256 contiguous
// bytes (~16 dwordx4 after LSV merging, L1-line reuse); (2) scalar
// 1 ch/thread, 2 nodes/block, 2048 blocks, LDS 20KB, NO min-waves bound
// (natural scalar footprint ~55 VGPR; if <=64 -> 8 waves/SIMD).
// Predict: VGPR 56-64, FETCH ~12MB (spills gone), VALUBusy >=45%,
// kernel ~16-22us + 3us transpose, dur ~85.

#define NN 4096
#define NC 128
#define NE 10

typedef float f4u __attribute__((ext_vector_type(4), aligned(4)));

// ---------------------------- static_for ---------------------------------------
template<typename F, int... Is>
__device__ __forceinline__ void sfor_impl(F&& f, std::integer_sequence<int, Is...>) {
  (f(std::integral_constant<int, Is>{}), ...);
}
template<int N, typename F>
__device__ __forceinline__ void sfor(F&& f) {
  sfor_impl((F&&)f, std::make_integer_sequence<int, N>{});
}

// ---------------------------- CG metadata (constexpr) --------------------------
constexpr int T_L1c[19]  = {0,0,0,1,1,1,1,1,1,1,2,2,2,2,2,2,2,2,3};
constexpr int T_L2c[19]  = {0,1,2,0,1,1,1,2,2,2,0,1,1,1,2,2,2,2,2};
constexpr int T_L3c[19]  = {0,1,2,1,0,1,2,1,2,3,2,1,2,3,0,1,2,3,1};
constexpr int T_OFFc[19] = {0,1,10,35,44,53,80,125,170,245,350,375,420,495,600,625,700,825,1000};
constexpr int AOFFc[3]   = {0,1,4};

constexpr int P2U_L1c[7]  = {0,0,1,1,1,2,2};
constexpr int P2U_L2c[7]  = {0,1,1,1,2,2,2};
constexpr int P2U_LOc[7]  = {0,1,0,1,1,0,1};
constexpr int P2U_TBLc[7] = {0,1,4,5,7,14,15};
constexpr int P2U_WAc[7]  = {0,1,3,4,5,7,8};
constexpr int P2U_WBc[7]  = {-1,2,-1,-1,6,-1,-1};

constexpr int K_L1c[18]  = {0,0,0,1,1,1,1,1,1,1,2,2,2,2,2,2,2,2};
constexpr int K_L2c[18]  = {0,1,2,0,1,1,1,2,2,2,0,1,1,1,2,2,2,2};
constexpr int K_L12c[18] = {0,1,2,1,0,1,2,1,2,3,2,1,2,3,0,1,2,3};

constexpr int   TT_CANONc[18] = {0,1,2,1,4,5,6,7,8,9,2,7,8,9,14,15,16,17};
constexpr float TT_SGNc[18]   = {1,1,1,1,1,1,1,1,1,1,1,1,-1,1,1,1,1,1};
constexpr int CANONc[13] = {0,1,2,4,5,6,7,8,9,14,15,16,17};
constexpr int CONS2c[13] = {-1,3,10,-1,-1,-1,11,12,13,-1,-1,-1,-1};

constexpr int P3_STARTc[19] = {0,2,6,9,13,15,19,22,26,29,30,33,37,40,41,43,47,50,51};
constexpr int P3_L3c[51] = {
  0,1,  0,1,1,2,  1,2,2,  0,1,1,2,  0,1,  0,1,1,2,  1,2,2,  0,1,1,2,  1,2,2,
  2,  1,2,2,  0,1,1,2,  1,2,2,  2,  0,1,  0,1,1,2,  1,2,2,  2 };
constexpr int P3_LOc[51] = {
  0,1,  1,0,1,1,  1,0,1,  1,0,1,1,  0,1,  1,0,1,1,  1,0,1,  1,0,1,1,  1,0,1,
  1,  1,0,1,  1,0,1,1,  1,0,1,  1,  0,1,  1,0,1,1,  1,0,1,  1 };
constexpr int P3_TBLc[51] = {
  0,1,  3,4,5,7,  11,14,15,  3,4,5,7,  0,1,  3,4,5,7,  11,14,15,  3,4,5,7,
  11,14,15,  18,  11,14,15,  3,4,5,7,  11,14,15,  18,  0,1,  3,4,5,7,
  11,14,15,  18 };

// ---------------------------- constexpr CG computation -------------------------
constexpr double cfact(int n) { double r = 1.0; for (int i = 2; i <= n; ++i) r *= i; return r; }
constexpr double csqrt(double x) {
  if (x <= 0.0) return 0.0;
  double r = x > 1.0 ? x : 1.0;
  for (int i = 0; i < 64; ++i) r = 0.5 * (r + x / r);
  return r;
}
constexpr double su2cg(int j1, int m1, int j2, int m2, int j3, int m3) {
  if (m3 != m1 + m2) return 0.0;
  int vmin = -j1 + j2 + m3; if (-j1 + m1 > vmin) vmin = -j1 + m1; if (vmin < 0) vmin = 0;
  int vmax = j2 + j3 + m1; if (j3 - j1 + j2 < vmax) vmax = j3 - j1 + j2; if (j3 + m3 < vmax) vmax = j3 + m3;
  double C = csqrt((2.0 * j3 + 1.0)
                   * cfact(j3 + j1 - j2) * cfact(j3 - j1 + j2) * cfact(j1 + j2 - j3)
                   * cfact(j3 + m3) * cfact(j3 - m3)
                   / (cfact(j1 + j2 + j3 + 1) * cfact(j1 - m1) * cfact(j1 + m1)
                      * cfact(j2 - m2) * cfact(j2 + m2)));
  double S = 0.0;
  for (int v = vmin; v <= vmax; ++v) {
    double sgn = ((v + j2 + m2) & 1) ? -1.0 : 1.0;
    S += sgn * cfact(j2 + j3 + m1 - v) * cfact(j1 - m1 + v)
         / (cfact(v) * cfact(j3 - j1 + j2 - v) * cfact(j3 + m3 - v) * cfact(v + j1 - j2 - m3));
  }
  return C * S;
}

struct Cx { double re, im; };
constexpr Cx cxmul(Cx a, Cx b) { return Cx{a.re * b.re - a.im * b.im, a.re * b.im + a.im * b.re}; }
struct Row { int cnt; int col[2]; Cx v[2]; };

constexpr Row c2r_row(int l, int r) {
  Row out{0, {0, 0}, {{0, 0}, {0, 0}}};
  constexpr double is2 = 0.70710678118654752440;
  const int m = r - l;
  if (m < 0) {
    out.cnt = 2;
    out.col[0] = l - m; out.v[0] = Cx{is2, 0.0};
    out.col[1] = l + m; out.v[1] = Cx{0.0, -is2};
  } else if (m == 0) {
    out.cnt = 1; out.col[0] = l; out.v[0] = Cx{1.0, 0.0};
  } else {
    const double sgn = (m & 1) ? -1.0 : 1.0;
    out.cnt = 2;
    out.col[0] = l + m; out.v[0] = Cx{sgn * is2, 0.0};
    out.col[1] = l - m; out.v[1] = Cx{0.0, sgn * is2};
  }
  const int ph = l & 3;
  for (int a = 0; a < out.cnt; ++a) {
    Cx v = out.v[a];
    out.v[a] = (ph == 0) ? v
             : (ph == 1) ? Cx{v.im, -v.re}
             : (ph == 2) ? Cx{-v.re, -v.im}
                         : Cx{-v.im, v.re};
  }
  return out;
}

struct CGAll { float v[1105]; };
constexpr CGAll make_cg() {
  CGAll R{};
  for (int t = 0; t < 19; ++t) {
    const int l1 = T_L1c[t], l2 = T_L2c[t], l3 = T_L3c[t], off = T_OFFc[t];
    const int d1 = 2 * l1 + 1, d2 = 2 * l2 + 1, d3 = 2 * l3 + 1;
    double tmp[175] = {};
    for (int i = 0; i < d1; ++i) {
      const int m1 = i - l1;
      const Row r1 = c2r_row(l1, i);
      for (int k = 0; k < d2; ++k) {
        const int m2 = k - l2, m3 = m1 + m2;
        if (m3 < -l3 || m3 > l3) continue;
        const double cc = su2cg(l1, m1, l2, m2, l3, m3);
        if (cc == 0.0) continue;
        const Row r2 = c2r_row(l2, k);
        const Row r3 = c2r_row(l3, m3 + l3);
        for (int a = 0; a < r1.cnt; ++a)
          for (int b = 0; b < r2.cnt; ++b) {
            const Cx q12 = cxmul(r1.v[a], r2.v[b]);
            for (int cdx = 0; cdx < r3.cnt; ++cdx) {
              const double re = q12.re * r3.v[cdx].re + q12.im * r3.v[cdx].im;
              tmp[(r1.col[a] * d2 + r2.col[b]) * d3 + r3.col[cdx]] += re * cc;
            }
          }
      }
    }
    const int sz = d1 * d2 * d3;
    for (int e = 0; e < sz; ++e) R.v[off + e] = (float)tmp[e];
  }
  return R;
}
constexpr CGAll CG_ALL = make_cg();

constexpr bool check_cg_sym() {
  for (int t = 0; t < 18; ++t) {
    const int tc = TT_CANONc[t];
    if (tc == t) continue;
    const int l1 = K_L1c[t], l2 = K_L2c[t], l12 = K_L12c[t];
    const int d1 = 2*l1+1, d2 = 2*l2+1, d12 = 2*l12+1;
    for (int i = 0; i < d1; ++i)
      for (int j = 0; j < d2; ++j)
        for (int k = 0; k < d12; ++k) {
          float a = CG_ALL.v[T_OFFc[t]  + (i*d2 + j)*d12 + k];
          float b = TT_SGNc[t] * CG_ALL.v[T_OFFc[tc] + (j*d1 + i)*d12 + k];
          float d = a - b; if (d < 0) d = -d;
          if (d > 1e-5f) return false;
        }
  }
  return true;
}
static_assert(check_cg_sym(), "CG exchange symmetry violated");

// ============================ weight transpose kernel ==========================
// wt[E][C][64]: j 0..1 = w1, 2..10 = w2, 11..61 = w3, 62..63 = pad.
// 81920 threads; lanes = consecutive c at fixed j -> coalesced reads.
__global__ __launch_bounds__(256) void epb_wt(
    const float* __restrict__ w1,   // [E, 2, C]
    const float* __restrict__ w2,   // [E, 9, C]
    const float* __restrict__ w3,   // [E, 51, C]
    float* __restrict__ wt)         // [E, C, 64]
{
  const int idx = blockIdx.x * 256 + threadIdx.x;   // e(4b) j(6b) c(7b)
  const int c = idx & 127;
  const int j = (idx >> 7) & 63;
  const int e = idx >> 13;
  float v = 0.f;
  if (j < 2)       v = w1[((size_t)e * 2  + j)       * NC + c];
  else if (j < 11) v = w2[((size_t)e * 9  + (j - 2)) * NC + c];
  else if (j < 62) v = w3[((size_t)e * 51 + (j - 11)) * NC + c];
  wt[((size_t)(e * NC + c)) * 64 + j] = v;
}

// ============================ fused basis + linear kernel ======================
// Block = 2 nodes x 256 threads (1 channel/thread), 2048 blocks.
// Phase A: t = node(t>>7) x channel(t&127); weights from wt (256B
// contiguous per thread); B (4 floats) -> Bsh 4KB.
// Phase B: t = (q = f-quad 0..31, wv = 32-ch chunk 0..3, node = t>>7);
// partials -> 16KB Red; 4-way tree-reduce + coalesced float4 store.
// NO min-waves bound — R15 proved forcing causes spill catastrophe.
__global__ __launch_bounds__(256) void epb_fused(
    const float*  __restrict__ nf,      // [N, C, 9]
    const float*  __restrict__ wt,      // [E, C, 64] packed w1|w2|w3
    const float4* __restrict__ lw0_4,   // [C, F/4]
    const float4* __restrict__ lw1_4,   // [C, F/4]
    const int*    __restrict__ species, // [N]
    float* __restrict__ out)            // [N, F, 4]
{
  __shared__ float4 Bsh[2 * NC];        //  4 KB  [node][channel] (m0..m3)
  __shared__ float4 Red[8 * NC];        // 16 KB  [node*4+f_local][chunk*32+q]

  const int t  = threadIdx.x;
  const int nb = blockIdx.x * 2;

  // ---------------- phase A: basis (scalar, 1 ch/thread) -------------------
  {
    const int nl = t >> 7;               // node 0/1 (wave-uniform)
    const int c  = t & 127;              // channel
    const int n  = nb + nl;
    const int s  = species[n];

    const float* ap = nf + ((size_t)n * NC + c) * 9;
    float A[9];
    {
      const f4u v0 = *reinterpret_cast<const f4u*>(ap);
      const f4u v1 = *reinterpret_cast<const f4u*>(ap + 4);
      sfor<4>([&](auto I) { A[I.value] = v0[I.value]; A[I.value + 4] = v1[I.value]; });
      A[8] = ap[8];
    }

    // all weights for this (s, c): 64 contiguous floats
    const float* wtp = wt + ((size_t)(s * NC + c)) * 64;

    float B[4];
    {
      const float wa = wtp[0], wb = wtp[1];
      B[0] = wa * A[0];
      B[1] = wb * A[1];
      B[2] = wb * A[2];
      B[3] = wb * A[3];
    }

    sfor<7>([&](auto P) {
      constexpr int p  = P.value;
      constexpr int l1 = P2U_L1c[p], l2 = P2U_L2c[p], lo = P2U_LOc[p];
      constexpr int d1 = 2*l1+1, d2 = 2*l2+1, dl = 2*lo+1;
      constexpr int off = T_OFFc[P2U_TBLc[p]];
      float w = wtp[2 + P2U_WAc[p]];
      if constexpr (P2U_WBc[p] >= 0) w += wtp[2 + P2U_WBc[p]];
      sfor<dl>([&](auto Kk) {
        constexpr int k = Kk.value;
        float v = 0.f;
        sfor<d1>([&](auto I) {
          sfor<d2>([&](auto J) {
            constexpr float cgc = CG_ALL.v[off + (I.value * d2 + J.value) * dl + k];
            if constexpr (cgc != 0.0f) {
              constexpr int ia = AOFFc[l1] + I.value, ja = AOFFc[l2] + J.value;
              constexpr int x = ia < ja ? ia : ja, y = ia < ja ? ja : ia;
              v = fmaf(cgc, A[x] * A[y], v);
            }
          });
        });
        B[lo + k] = fmaf(w, v, B[lo + k]);
      });
    });

    sfor<13>([&](auto CI) {
      constexpr int tk  = CANONc[CI.value];
      constexpr int l1  = K_L1c[tk], l2 = K_L2c[tk], l12 = K_L12c[tk];
      constexpr int d1  = 2*l1+1, d2 = 2*l2+1, d12 = 2*l12+1;
      constexpr int off = T_OFFc[tk];
      float tt[d12];
      sfor<d12>([&](auto Kk) {
        constexpr int k = Kk.value;
        float v = 0.f;
        sfor<d1>([&](auto I) {
          sfor<d2>([&](auto J) {
            constexpr float cgc = CG_ALL.v[off + (I.value * d2 + J.value) * d12 + k];
            if constexpr (cgc != 0.0f) {
              constexpr int ia = AOFFc[l1] + I.value, ja = AOFFc[l2] + J.value;
              constexpr int x = ia < ja ? ia : ja, y = ia < ja ? ja : ia;
              v = fmaf(cgc, A[x] * A[y], v);
            }
          });
        });
        tt[k] = v;
      });

      auto consume = [&](auto TK, auto SG) {
        constexpr int tkey = TK.value;
        constexpr float sgn = (float)SG.value;
        constexpr int pcnt = P3_STARTc[tkey + 1] - P3_STARTc[tkey];
        sfor<pcnt>([&](auto PP) {
          constexpr int p  = P3_STARTc[tkey] + PP.value;
          constexpr int l3 = P3_L3c[p], lo = P3_LOc[p];
          constexpr int d3 = 2*l3+1, dl = 2*lo+1;
          constexpr int off2 = T_OFFc[P3_TBLc[p]];
          const float w = wtp[11 + p];
          sfor<dl>([&](auto M) {
            float v = 0.f;
            sfor<d12>([&](auto Kk) {
              sfor<d3>([&](auto J) {
                constexpr float cgc = sgn * CG_ALL.v[off2 + (Kk.value * d3 + J.value) * dl + M.value];
                if constexpr (cgc != 0.0f)
                  v = fmaf(cgc, tt[Kk.value] * A[AOFFc[l3] + J.value], v);
              });
            });
            B[lo + M.value] = fmaf(w, v, B[lo + M.value]);
          });
        });
      };
      consume(std::integral_constant<int, tk>{}, std::integral_constant<int, 1>{});
      constexpr int td = CONS2c[CI.value];
      if constexpr (td >= 0)
        consume(std::integral_constant<int, td>{},
                std::integral_constant<int, (int)TT_SGNc[td]>{});
    });

    Bsh[nl * NC + c] = make_float4(B[0], B[1], B[2], B[3]);
  }
  __syncthreads();

  // ---------------- phase B: equivariant linear -----------------------------
  // thread -> (q = f-quad 0..31, wv = 32-ch chunk 0..3, nl2 = node 0/1)
  const int q   = t & 31;
  const int wv  = (t >> 5) & 3;
  const int nl2 = t >> 7;

  float4 acc[4] = {};                    // [f_local], comps in float4

  const float4* w0c = lw0_4 + (size_t)(wv * 32) * 32 + q;
  const float4* w1c = lw1_4 + (size_t)(wv * 32) * 32 + q;
  const float4* bp  = &Bsh[nl2 * NC + wv * 32];

  #pragma unroll 4
  for (int i = 0; i < 32; ++i) {
    const float4 wa = w0c[i * 32];       // 32 consecutive float4/half-wave -> coalesced
    const float4 wb = w1c[i * 32];
    const float4 b  = bp[i];             // 2 uniform addrs/wave -> broadcast
    acc[0].x = fmaf(b.x, wa.x, acc[0].x); acc[0].y = fmaf(b.y, wb.x, acc[0].y);
    acc[0].z = fmaf(b.z, wb.x, acc[0].z); acc[0].w = fmaf(b.w, wb.x, acc[0].w);
    acc[1].x = fmaf(b.x, wa.y, acc[1].x); acc[1].y = fmaf(b.y, wb.y, acc[1].y);
    acc[1].z = fmaf(b.z, wb.y, acc[1].z); acc[1].w = fmaf(b.w, wb.y, acc[1].w);
    acc[2].x = fmaf(b.x, wa.z, acc[2].x); acc[2].y = fmaf(b.y, wb.z, acc[2].y);
    acc[2].z = fmaf(b.z, wb.z, acc[2].z); acc[2].w = fmaf(b.w, wb.z, acc[2].w);
    acc[3].x = fmaf(b.x, wa.w, acc[3].x); acc[3].y = fmaf(b.y, wb.w, acc[3].y);
    acc[3].z = fmaf(b.z, wb.w, acc[3].z); acc[3].w = fmaf(b.w, wb.w, acc[3].w);
  }

  // partials: lanes of each write instr cover 64 consecutive float4 -> 1KB
  // contiguous, conflict-free.
  sfor<4>([&](auto F_) {
    Red[(nl2 * 4 + F_.value) * NC + wv * 32 + q] = acc[F_.value];
  });
  __syncthreads();

  // 4-way tree reduce + scale + coalesced store (1 float4 output per thread)
  const float s4 = 0.08838834764831845f;  // 1/sqrt(128)
  float4* o4 = reinterpret_cast<float4*>(out);
  {
    const int n   = t >> 7;               // node in block
    const int rem = t & 127;              // feature index
    const int row = (n * 4 + (rem & 3)) * NC + (rem >> 2);
    const float4 r0 = Red[row];
    const float4 r1 = Red[row + 32];
    const float4 r2 = Red[row + 64];
    const float4 r3 = Red[row + 96];
    o4[(size_t)(nb + n) * NC + rem] = make_float4(
        ((r0.x + r1.x) + (r2.x + r3.x)) * s4,
        ((r0.y + r1.y) + (r2.y + r3.y)) * s4,
        ((r0.z + r1.z) + (r2.z + r3.z)) * s4,
        ((r0.w + r1.w) + (r2.w + r3.w)) * s4);
  }
}

// ------------------------------- launcher --------------------------------------
extern "C" void kernel_launch(void* const* d_in, const int* in_sizes, int n_in,
                              void* d_out, int out_size, void* d_ws, size_t ws_size,
                              hipStream_t stream) {
  const float* nf  = (const float*)d_in[0];
  const float* w1  = (const float*)d_in[1];
  const float* w2  = (const float*)d_in[2];
  const float* w3  = (const float*)d_in[3];
  const float* lw0 = (const float*)d_in[4];
  const float* lw1 = (const float*)d_in[5];
  const int*   spc = (const int*)  d_in[6];
  float* out = (float*)d_out;
  float* wt  = (float*)d_ws;            // [E, C, 64] = 327,680 B of workspace
  (void)ws_size; (void)in_sizes; (void)n_in; (void)out_size;

  hipLaunchKernelGGL(epb_wt, dim3(NE * NC * 64 / 256), dim3(256), 0, stream,
                     w1, w2, w3, wt);
  hipLaunchKernelGGL(epb_fused, dim3(NN / 2), dim3(256), 0, stream,
                     nf, wt, (const float4*)lw0, (const float4*)lw1,
                     spc, out);
}

// Round 6
// 110.662 us; speedup vs baseline: 2.2172x; 1.0074x over previous
//
#include <hip/hip_runtime.h>
#include <utility>

// EquivariantProductBasisBlock (MACE-style) for gfx950 — round 17.
// R16 post-mortem: scalar rewrite raised VALU-issue 10.5->18.2us (v2f pack
// really halves inst count) and VGPR to 96 (compiler clusters the 64-float
// contiguous weight block); 54us > R14 45.7 > R12 ~40. Best = R12 (v2f,
// 4 nodes, no bounds). Cross-round model: wall ~= VALU-busy / (~6.5% per
// resident wave/SIMD); R12/R14 capped at 4 blocks/CU by LDS=40KB (Red
// buffer is 32KB of it), not VGPR.
// R17: keep v2f phase A (cheapest inst stream) and fix both drags:
// (1) weight packing for PAIRS: wt[E][C/2][64][2] -> a v2f thread's whole
//     weight stream is 512 contiguous bytes (ld2 at offsets 0,2,..,122;
//     LSV merges into dwordx4 runs) vs 62 loads at 512B stride;
// (2) phase B reduction partners in the SAME WAVE (lane halves h=0/1,
//     one shfl_xor(32)) -> Red LDS eliminated: LDS 40KB -> 8KB (Bsh only),
//     barriers 2 -> 1; blocks/CU now VGPR-limited ~5-6 waves/SIMD.
// Predict: LDS 8192, VGPR 84-96, Occ >=30%, VALUBusy >=35%, kernel ~30us,
// dur ~88. If kernel ~40 despite this, occupancy/latency theories both die
// -> next round is a phase-split ablation.

#define NN 4096
#define NC 128
#define NE 10

typedef float v2f __attribute__((ext_vector_type(2)));

__device__ __forceinline__ v2f ld2(const float* p) {
  return *reinterpret_cast<const v2f*>(p);
}
__device__ __forceinline__ v2f cfma(float c, v2f x, v2f a) {  // a += c*x (splat c)
  v2f cc = {c, c};
  return __builtin_elementwise_fma(cc, x, a);
}
__device__ __forceinline__ v2f vfma(v2f w, v2f x, v2f a) {    // a += w*x
  return __builtin_elementwise_fma(w, x, a);
}

// ---------------------------- static_for ---------------------------------------
template<typename F, int... Is>
__device__ __forceinline__ void sfor_impl(F&& f, std::integer_sequence<int, Is...>) {
  (f(std::integral_constant<int, Is>{}), ...);
}
template<int N, typename F>
__device__ __forceinline__ void sfor(F&& f) {
  sfor_impl((F&&)f, std::make_integer_sequence<int, N>{});
}

// ---------------------------- CG metadata (constexpr) --------------------------
constexpr int T_L1c[19]  = {0,0,0,1,1,1,1,1,1,1,2,2,2,2,2,2,2,2,3};
constexpr int T_L2c[19]  = {0,1,2,0,1,1,1,2,2,2,0,1,1,1,2,2,2,2,2};
constexpr int T_L3c[19]  = {0,1,2,1,0,1,2,1,2,3,2,1,2,3,0,1,2,3,1};
constexpr int T_OFFc[19] = {0,1,10,35,44,53,80,125,170,245,350,375,420,495,600,625,700,825,1000};
constexpr int AOFFc[3]   = {0,1,4};

constexpr int P2U_L1c[7]  = {0,0,1,1,1,2,2};
constexpr int P2U_L2c[7]  = {0,1,1,1,2,2,2};
constexpr int P2U_LOc[7]  = {0,1,0,1,1,0,1};
constexpr int P2U_TBLc[7] = {0,1,4,5,7,14,15};
constexpr int P2U_WAc[7]  = {0,1,3,4,5,7,8};
constexpr int P2U_WBc[7]  = {-1,2,-1,-1,6,-1,-1};

constexpr int K_L1c[18]  = {0,0,0,1,1,1,1,1,1,1,2,2,2,2,2,2,2,2};
constexpr int K_L2c[18]  = {0,1,2,0,1,1,1,2,2,2,0,1,1,1,2,2,2,2};
constexpr int K_L12c[18] = {0,1,2,1,0,1,2,1,2,3,2,1,2,3,0,1,2,3};

constexpr int   TT_CANONc[18] = {0,1,2,1,4,5,6,7,8,9,2,7,8,9,14,15,16,17};
constexpr float TT_SGNc[18]   = {1,1,1,1,1,1,1,1,1,1,1,1,-1,1,1,1,1,1};
constexpr int CANONc[13] = {0,1,2,4,5,6,7,8,9,14,15,16,17};
constexpr int CONS2c[13] = {-1,3,10,-1,-1,-1,11,12,13,-1,-1,-1,-1};

constexpr int P3_STARTc[19] = {0,2,6,9,13,15,19,22,26,29,30,33,37,40,41,43,47,50,51};
constexpr int P3_L3c[51] = {
  0,1,  0,1,1,2,  1,2,2,  0,1,1,2,  0,1,  0,1,1,2,  1,2,2,  0,1,1,2,  1,2,2,
  2,  1,2,2,  0,1,1,2,  1,2,2,  2,  0,1,  0,1,1,2,  1,2,2,  2 };
constexpr int P3_LOc[51] = {
  0,1,  1,0,1,1,  1,0,1,  1,0,1,1,  0,1,  1,0,1,1,  1,0,1,  1,0,1,1,  1,0,1,
  1,  1,0,1,  1,0,1,1,  1,0,1,  1,  0,1,  1,0,1,1,  1,0,1,  1 };
constexpr int P3_TBLc[51] = {
  0,1,  3,4,5,7,  11,14,15,  3,4,5,7,  0,1,  3,4,5,7,  11,14,15,  3,4,5,7,
  11,14,15,  18,  11,14,15,  3,4,5,7,  11,14,15,  18,  0,1,  3,4,5,7,
  11,14,15,  18 };

// ---------------------------- constexpr CG computation -------------------------
constexpr double cfact(int n) { double r = 1.0; for (int i = 2; i <= n; ++i) r *= i; return r; }
constexpr double csqrt(double x) {
  if (x <= 0.0) return 0.0;
  double r = x > 1.0 ? x : 1.0;
  for (int i = 0; i < 64; ++i) r = 0.5 * (r + x / r);
  return r;
}
constexpr double su2cg(int j1, int m1, int j2, int m2, int j3, int m3) {
  if (m3 != m1 + m2) return 0.0;
  int vmin = -j1 + j2 + m3; if (-j1 + m1 > vmin) vmin = -j1 + m1; if (vmin < 0) vmin = 0;
  int vmax = j2 + j3 + m1; if (j3 - j1 + j2 < vmax) vmax = j3 - j1 + j2; if (j3 + m3 < vmax) vmax = j3 + m3;
  double C = csqrt((2.0 * j3 + 1.0)
                   * cfact(j3 + j1 - j2) * cfact(j3 - j1 + j2) * cfact(j1 + j2 - j3)
                   * cfact(j3 + m3) * cfact(j3 - m3)
                   / (cfact(j1 + j2 + j3 + 1) * cfact(j1 - m1) * cfact(j1 + m1)
                      * cfact(j2 - m2) * cfact(j2 + m2)));
  double S = 0.0;
  for (int v = vmin; v <= vmax; ++v) {
    double sgn = ((v + j2 + m2) & 1) ? -1.0 : 1.0;
    S += sgn * cfact(j2 + j3 + m1 - v) * cfact(j1 - m1 + v)
         / (cfact(v) * cfact(j3 - j1 + j2 - v) * cfact(j3 + m3 - v) * cfact(v + j1 - j2 - m3));
  }
  return C * S;
}

struct Cx { double re, im; };
constexpr Cx cxmul(Cx a, Cx b) { return Cx{a.re * b.re - a.im * b.im, a.re * b.im + a.im * b.re}; }
struct Row { int cnt; int col[2]; Cx v[2]; };

constexpr Row c2r_row(int l, int r) {
  Row out{0, {0, 0}, {{0, 0}, {0, 0}}};
  constexpr double is2 = 0.70710678118654752440;
  const int m = r - l;
  if (m < 0) {
    out.cnt = 2;
    out.col[0] = l - m; out.v[0] = Cx{is2, 0.0};
    out.col[1] = l + m; out.v[1] = Cx{0.0, -is2};
  } else if (m == 0) {
    out.cnt = 1; out.col[0] = l; out.v[0] = Cx{1.0, 0.0};
  } else {
    const double sgn = (m & 1) ? -1.0 : 1.0;
    out.cnt = 2;
    out.col[0] = l + m; out.v[0] = Cx{sgn * is2, 0.0};
    out.col[1] = l - m; out.v[1] = Cx{0.0, sgn * is2};
  }
  const int ph = l & 3;
  for (int a = 0; a < out.cnt; ++a) {
    Cx v = out.v[a];
    out.v[a] = (ph == 0) ? v
             : (ph == 1) ? Cx{v.im, -v.re}
             : (ph == 2) ? Cx{-v.re, -v.im}
                         : Cx{-v.im, v.re};
  }
  return out;
}

struct CGAll { float v[1105]; };
constexpr CGAll make_cg() {
  CGAll R{};
  for (int t = 0; t < 19; ++t) {
    const int l1 = T_L1c[t], l2 = T_L2c[t], l3 = T_L3c[t], off = T_OFFc[t];
    const int d1 = 2 * l1 + 1, d2 = 2 * l2 + 1, d3 = 2 * l3 + 1;
    double tmp[175] = {};
    for (int i = 0; i < d1; ++i) {
      const int m1 = i - l1;
      const Row r1 = c2r_row(l1, i);
      for (int k = 0; k < d2; ++k) {
        const int m2 = k - l2, m3 = m1 + m2;
        if (m3 < -l3 || m3 > l3) continue;
        const double cc = su2cg(l1, m1, l2, m2, l3, m3);
        if (cc == 0.0) continue;
        const Row r2 = c2r_row(l2, k);
        const Row r3 = c2r_row(l3, m3 + l3);
        for (int a = 0; a < r1.cnt; ++a)
          for (int b = 0; b < r2.cnt; ++b) {
            const Cx q12 = cxmul(r1.v[a], r2.v[b]);
            for (int cdx = 0; cdx < r3.cnt; ++cdx) {
              const double re = q12.re * r3.v[cdx].re + q12.im * r3.v[cdx].im;
              tmp[(r1.col[a] * d2 + r2.col[b]) * d3 + r3.col[cdx]] += re * cc;
            }
          }
      }
    }
    const int sz = d1 * d2 * d3;
    for (int e = 0; e < sz; ++e) R.v[off + e] = (float)tmp[e];
  }
  return R;
}
constexpr CGAll CG_ALL = make_cg();

constexpr bool check_cg_sym() {
  for (int t = 0; t < 18; ++t) {
    const int tc = TT_CANONc[t];
    if (tc == t) continue;
    const int l1 = K_L1c[t], l2 = K_L2c[t], l12 = K_L12c[t];
    const int d1 = 2*l1+1, d2 = 2*l2+1, d12 = 2*l12+1;
    for (int i = 0; i < d1; ++i)
      for (int j = 0; j < d2; ++j)
        for (int k = 0; k < d12; ++k) {
          float a = CG_ALL.v[T_OFFc[t]  + (i*d2 + j)*d12 + k];
          float b = TT_SGNc[t] * CG_ALL.v[T_OFFc[tc] + (j*d1 + i)*d12 + k];
          float d = a - b; if (d < 0) d = -d;
          if (d > 1e-5f) return false;
        }
  }
  return true;
}
static_assert(check_cg_sym(), "CG exchange symmetry violated");

// ============================ weight transpose kernel ==========================
// wt[E][C/2][64][2]: per channel-PAIR cp, 64 path slots j, 2 channels
// interleaved -> a v2f phase-A thread reads 512 CONTIGUOUS bytes.
// j 0..1 = w1, 2..10 = w2, 11..61 = w3, 62..63 = pad.
__global__ __launch_bounds__(256) void epb_wt(
    const float* __restrict__ w1,   // [E, 2, C]
    const float* __restrict__ w2,   // [E, 9, C]
    const float* __restrict__ w3,   // [E, 51, C]
    float* __restrict__ wt)         // [E, C/2, 64, 2]
{
  const int idx = blockIdx.x * 256 + threadIdx.x;   // e(4b) cp(6b) j(6b) b(1b)
  const int b  = idx & 1;
  const int j  = (idx >> 1) & 63;
  const int cp = (idx >> 7) & 63;
  const int e  = idx >> 13;
  const int c  = cp * 2 + b;
  float v = 0.f;
  if (j < 2)       v = w1[((size_t)e * 2  + j)        * NC + c];
  else if (j < 11) v = w2[((size_t)e * 9  + (j - 2))  * NC + c];
  else if (j < 62) v = w3[((size_t)e * 51 + (j - 11)) * NC + c];
  wt[idx] = v;
}

// ============================ fused basis + linear kernel ======================
// Block = 4 nodes x 256 threads, 1024 blocks. LDS = Bsh only (8KB).
// Phase A (v2f): wave nl owns node nb+nl, lanes own channel pairs; weights
// from wt = 512 contiguous bytes/thread; B -> Bsh.
// Phase B: wave nl owns node nb+nl; lane = (q = f-quad 0..31, h = channel
// half 0/1); each lane sums 64 channels; one shfl_xor(32) completes the
// reduction in-wave; lanes h==0 store. No Red, no second barrier.
__global__ __launch_bounds__(256) void epb_fused(
    const float*  __restrict__ nf,      // [N, C, 9]
    const float*  __restrict__ wt,      // [E, C/2, 64, 2]
    const float4* __restrict__ lw0_4,   // [C, F/4]
    const float4* __restrict__ lw1_4,   // [C, F/4]
    const int*    __restrict__ species, // [N]
    float* __restrict__ out)            // [N, F, 4]
{
  __shared__ float4 Bsh[4 * NC];        // 8 KB  [node][channel] (m0..m3)

  const int t  = threadIdx.x;
  const int nb = blockIdx.x * 4;

  // ---------------- phase A: basis (v2f, 2 ch/thread) ----------------------
  {
    const int nl = t >> 6;               // wave-uniform node
    const int cp = t & 63;               // channel pair
    const int c0 = cp * 2;
    const int n  = nb + nl;
    const int s  = species[n];

    const float* ap = nf + ((size_t)n * NC + c0) * 9;
    v2f A[9];
    sfor<9>([&](auto I) { A[I.value] = v2f{ap[I.value], ap[I.value + 9]}; });

    // all weights for (s, c0..c0+1): 128 contiguous floats; path j at +2j
    const float* wtp = wt + ((size_t)(s * 64 + cp)) * 128;

    v2f B[4];
    {
      const v2f wa = ld2(wtp + 0), wb = ld2(wtp + 2);
      B[0] = wa * A[0];
      B[1] = wb * A[1];
      B[2] = wb * A[2];
      B[3] = wb * A[3];
    }

    sfor<7>([&](auto P) {
      constexpr int p  = P.value;
      constexpr int l1 = P2U_L1c[p], l2 = P2U_L2c[p], lo = P2U_LOc[p];
      constexpr int d1 = 2*l1+1, d2 = 2*l2+1, dl = 2*lo+1;
      constexpr int off = T_OFFc[P2U_TBLc[p]];
      v2f w = ld2(wtp + 2 * (2 + P2U_WAc[p]));
      if constexpr (P2U_WBc[p] >= 0) w = w + ld2(wtp + 2 * (2 + P2U_WBc[p]));
      sfor<dl>([&](auto Kk) {
        constexpr int k = Kk.value;
        v2f v = {0.f, 0.f};
        sfor<d1>([&](auto I) {
          sfor<d2>([&](auto J) {
            constexpr float cgc = CG_ALL.v[off + (I.value * d2 + J.value) * dl + k];
            if constexpr (cgc != 0.0f) {
              constexpr int ia = AOFFc[l1] + I.value, ja = AOFFc[l2] + J.value;
              constexpr int x = ia < ja ? ia : ja, y = ia < ja ? ja : ia;
              v = cfma(cgc, A[x] * A[y], v);
            }
          });
        });
        B[lo + k] = vfma(w, v, B[lo + k]);
      });
    });

    sfor<13>([&](auto CI) {
      constexpr int tk  = CANONc[CI.value];
      constexpr int l1  = K_L1c[tk], l2 = K_L2c[tk], l12 = K_L12c[tk];
      constexpr int d1  = 2*l1+1, d2 = 2*l2+1, d12 = 2*l12+1;
      constexpr int off = T_OFFc[tk];
      v2f tt[d12];
      sfor<d12>([&](auto Kk) {
        constexpr int k = Kk.value;
        v2f v = {0.f, 0.f};
        sfor<d1>([&](auto I) {
          sfor<d2>([&](auto J) {
            constexpr float cgc = CG_ALL.v[off + (I.value * d2 + J.value) * d12 + k];
            if constexpr (cgc != 0.0f) {
              constexpr int ia = AOFFc[l1] + I.value, ja = AOFFc[l2] + J.value;
              constexpr int x = ia < ja ? ia : ja, y = ia < ja ? ja : ia;
              v = cfma(cgc, A[x] * A[y], v);
            }
          });
        });
        tt[k] = v;
      });

      auto consume = [&](auto TK, auto SG) {
        constexpr int tkey = TK.value;
        constexpr float sgn = (float)SG.value;
        constexpr int pcnt = P3_STARTc[tkey + 1] - P3_STARTc[tkey];
        sfor<pcnt>([&](auto PP) {
          constexpr int p  = P3_STARTc[tkey] + PP.value;
          constexpr int l3 = P3_L3c[p], lo = P3_LOc[p];
          constexpr int d3 = 2*l3+1, dl = 2*lo+1;
          constexpr int off2 = T_OFFc[P3_TBLc[p]];
          const v2f w = ld2(wtp + 2 * (11 + p));
          sfor<dl>([&](auto M) {
            v2f v = {0.f, 0.f};
            sfor<d12>([&](auto Kk) {
              sfor<d3>([&](auto J) {
                constexpr float cgc = sgn * CG_ALL.v[off2 + (Kk.value * d3 + J.value) * dl + M.value];
                if constexpr (cgc != 0.0f)
                  v = cfma(cgc, tt[Kk.value] * A[AOFFc[l3] + J.value], v);
              });
            });
            B[lo + M.value] = vfma(w, v, B[lo + M.value]);
          });
        });
      };
      consume(std::integral_constant<int, tk>{}, std::integral_constant<int, 1>{});
      constexpr int td = CONS2c[CI.value];
      if constexpr (td >= 0)
        consume(std::integral_constant<int, td>{},
                std::integral_constant<int, (int)TT_SGNc[td]>{});
    });

    Bsh[nl * NC + c0]     = make_float4(B[0].x, B[1].x, B[2].x, B[3].x);
    Bsh[nl * NC + c0 + 1] = make_float4(B[0].y, B[1].y, B[2].y, B[3].y);
  }
  __syncthreads();

  // ---------------- phase B: equivariant linear -----------------------------
  // wave nl -> node nb+nl; lane = q (f-quad, 0..31) + 32*h (channel half)
  const int nl2 = t >> 6;
  const int ln  = t & 63;
  const int q   = ln & 31;
  const int h   = ln >> 5;

  float4 acc[4] = {};                    // [f_local], comps in float4

  const float4* w0c = lw0_4 + (size_t)(h * 64) * 32 + q;
  const float4* w1c = lw1_4 + (size_t)(h * 64) * 32 + q;
  const float4* bp  = &Bsh[nl2 * NC + h * 64];

  #pragma unroll 4
  for (int i = 0; i < 64; ++i) {
    const float4 wa = w0c[i * 32];       // per half: 32 consecutive float4 -> coalesced
    const float4 wb = w1c[i * 32];
    const float4 b  = bp[i];             // 2 uniform addrs/wave -> broadcast
    acc[0].x = fmaf(b.x, wa.x, acc[0].x); acc[0].y = fmaf(b.y, wb.x, acc[0].y);
    acc[0].z = fmaf(b.z, wb.x, acc[0].z); acc[0].w = fmaf(b.w, wb.x, acc[0].w);
    acc[1].x = fmaf(b.x, wa.y, acc[1].x); acc[1].y = fmaf(b.y, wb.y, acc[1].y);
    acc[1].z = fmaf(b.z, wb.y, acc[1].z); acc[1].w = fmaf(b.w, wb.y, acc[1].w);
    acc[2].x = fmaf(b.x, wa.z, acc[2].x); acc[2].y = fmaf(b.y, wb.z, acc[2].y);
    acc[2].z = fmaf(b.z, wb.z, acc[2].z); acc[2].w = fmaf(b.w, wb.z, acc[2].w);
    acc[3].x = fmaf(b.x, wa.w, acc[3].x); acc[3].y = fmaf(b.y, wb.w, acc[3].y);
    acc[3].z = fmaf(b.z, wb.w, acc[3].z); acc[3].w = fmaf(b.w, wb.w, acc[3].w);
  }

  // in-wave reduction across channel halves: partner = lane ^ 32
  sfor<4>([&](auto F_) {
    constexpr int f = F_.value;
    acc[f].x += __shfl_xor(acc[f].x, 32);
    acc[f].y += __shfl_xor(acc[f].y, 32);
    acc[f].z += __shfl_xor(acc[f].z, 32);
    acc[f].w += __shfl_xor(acc[f].w, 32);
  });

  if (h == 0) {
    const float s4 = 0.08838834764831845f;  // 1/sqrt(128)
    float4* o4 = reinterpret_cast<float4*>(out) + (size_t)(nb + nl2) * NC + 4 * q;
    o4[0] = make_float4(acc[0].x*s4, acc[0].y*s4, acc[0].z*s4, acc[0].w*s4);
    o4[1] = make_float4(acc[1].x*s4, acc[1].y*s4, acc[1].z*s4, acc[1].w*s4);
    o4[2] = make_float4(acc[2].x*s4, acc[2].y*s4, acc[2].z*s4, acc[2].w*s4);
    o4[3] = make_float4(acc[3].x*s4, acc[3].y*s4, acc[3].z*s4, acc[3].w*s4);
  }
}

// ------------------------------- launcher --------------------------------------
extern "C" void kernel_launch(void* const* d_in, const int* in_sizes, int n_in,
                              void* d_out, int out_size, void* d_ws, size_t ws_size,
                              hipStream_t stream) {
  const float* nf  = (const float*)d_in[0];
  const float* w1  = (const float*)d_in[1];
  const float* w2  = (const float*)d_in[2];
  const float* w3  = (const float*)d_in[3];
  const float* lw0 = (const float*)d_in[4];
  const float* lw1 = (const float*)d_in[5];
  const int*   spc = (const int*)  d_in[6];
  float* out = (float*)d_out;
  float* wt  = (float*)d_ws;            // [E, C/2, 64, 2] = 320 KB of workspace
  (void)ws_size; (void)in_sizes; (void)n_in; (void)out_size;

  hipLaunchKernelGGL(epb_wt, dim3(NE * NC * 64 / 256), dim3(256), 0, stream,
                     w1, w2, w3, wt);
  hipLaunchKernelGGL(epb_fused, dim3(NN / 4), dim3(256), 0, stream,
                     nf, wt, (const float4*)lw0, (const float4*)lw1,
                     spc, out);
}

// Round 7
// 106.230 us; speedup vs baseline: 2.3097x; 1.0417x over previous
//
#include <hip/hip_runtime.h>
#include <utility>

// EquivariantProductBasisBlock (MACE-style) for gfx950 — round 18.
// R17 post-mortem: LDS 40K->8K + 1 barrier changed nothing (44.8 vs 45.7us);
// occupancy pinned at 4 waves/SIMD by VGPR=96>64 (8-wave needs <=64 which
// spills — R15/R16). wt packing was a mistake: per-THREAD contiguity killed
// per-LANE coalescing (orig [paths][C] layout was already coalesced).
// Synthesis: fused always ~40-45us > sum of parts (basis 18 standalone);
// phase B ~25us in all variants because it either streams 268MB of weights
// from L2 per iter or pays 3 LDS reads per 16 FMA (R11).
// R18: SPLIT. (1) epb_basis = exact R9/R11 kernel (measured 18us).
// (2) epb_linear = GEMM-tiled: 16 nodes/block (256 blocks), thread owns
// 2 nodes x 4f x 4comp = 32 acc -> 32 FMA per 4 LDS b128 (2 broadcast);
// W chunk (32ch, 32KB) + B tile (8KB) staged per phase; weight L2 traffic
// 268MB -> 32MB. 1 block/CU, ILP from the 32-acc tile carries it.
// Predict: basis ~18us, linear ~6-10us (VALUBusy>=45%), dur ~86-92.

#define NN 4096
#define NC 128
#define NE 10
#define LTN 16   // nodes per linear block

typedef float v2f __attribute__((ext_vector_type(2)));

__device__ __forceinline__ v2f ld2(const float* p) {
  return *reinterpret_cast<const v2f*>(p);
}
__device__ __forceinline__ v2f cfma(float c, v2f x, v2f a) {  // a += c*x (splat c)
  v2f cc = {c, c};
  return __builtin_elementwise_fma(cc, x, a);
}
__device__ __forceinline__ v2f vfma(v2f w, v2f x, v2f a) {    // a += w*x
  return __builtin_elementwise_fma(w, x, a);
}

// ---------------------------- static_for ---------------------------------------
template<typename F, int... Is>
__device__ __forceinline__ void sfor_impl(F&& f, std::integer_sequence<int, Is...>) {
  (f(std::integral_constant<int, Is>{}), ...);
}
template<int N, typename F>
__device__ __forceinline__ void sfor(F&& f) {
  sfor_impl((F&&)f, std::make_integer_sequence<int, N>{});
}

// ---------------------------- CG metadata (constexpr) --------------------------
constexpr int T_L1c[19]  = {0,0,0,1,1,1,1,1,1,1,2,2,2,2,2,2,2,2,3};
constexpr int T_L2c[19]  = {0,1,2,0,1,1,1,2,2,2,0,1,1,1,2,2,2,2,2};
constexpr int T_L3c[19]  = {0,1,2,1,0,1,2,1,2,3,2,1,2,3,0,1,2,3,1};
constexpr int T_OFFc[19] = {0,1,10,35,44,53,80,125,170,245,350,375,420,495,600,625,700,825,1000};
constexpr int AOFFc[3]   = {0,1,4};

constexpr int P2U_L1c[7]  = {0,0,1,1,1,2,2};
constexpr int P2U_L2c[7]  = {0,1,1,1,2,2,2};
constexpr int P2U_LOc[7]  = {0,1,0,1,1,0,1};
constexpr int P2U_TBLc[7] = {0,1,4,5,7,14,15};
constexpr int P2U_WAc[7]  = {0,1,3,4,5,7,8};
constexpr int P2U_WBc[7]  = {-1,2,-1,-1,6,-1,-1};

constexpr int K_L1c[18]  = {0,0,0,1,1,1,1,1,1,1,2,2,2,2,2,2,2,2};
constexpr int K_L2c[18]  = {0,1,2,0,1,1,1,2,2,2,0,1,1,1,2,2,2,2};
constexpr int K_L12c[18] = {0,1,2,1,0,1,2,1,2,3,2,1,2,3,0,1,2,3};

constexpr int   TT_CANONc[18] = {0,1,2,1,4,5,6,7,8,9,2,7,8,9,14,15,16,17};
constexpr float TT_SGNc[18]   = {1,1,1,1,1,1,1,1,1,1,1,1,-1,1,1,1,1,1};
constexpr int CANONc[13] = {0,1,2,4,5,6,7,8,9,14,15,16,17};
constexpr int CONS2c[13] = {-1,3,10,-1,-1,-1,11,12,13,-1,-1,-1,-1};

constexpr int P3_STARTc[19] = {0,2,6,9,13,15,19,22,26,29,30,33,37,40,41,43,47,50,51};
constexpr int P3_L3c[51] = {
  0,1,  0,1,1,2,  1,2,2,  0,1,1,2,  0,1,  0,1,1,2,  1,2,2,  0,1,1,2,  1,2,2,
  2,  1,2,2,  0,1,1,2,  1,2,2,  2,  0,1,  0,1,1,2,  1,2,2,  2 };
constexpr int P3_LOc[51] = {
  0,1,  1,0,1,1,  1,0,1,  1,0,1,1,  0,1,  1,0,1,1,  1,0,1,  1,0,1,1,  1,0,1,
  1,  1,0,1,  1,0,1,1,  1,0,1,  1,  0,1,  1,0,1,1,  1,0,1,  1 };
constexpr int P3_TBLc[51] = {
  0,1,  3,4,5,7,  11,14,15,  3,4,5,7,  0,1,  3,4,5,7,  11,14,15,  3,4,5,7,
  11,14,15,  18,  11,14,15,  3,4,5,7,  11,14,15,  18,  0,1,  3,4,5,7,
  11,14,15,  18 };

// ---------------------------- constexpr CG computation -------------------------
constexpr double cfact(int n) { double r = 1.0; for (int i = 2; i <= n; ++i) r *= i; return r; }
constexpr double csqrt(double x) {
  if (x <= 0.0) return 0.0;
  double r = x > 1.0 ? x : 1.0;
  for (int i = 0; i < 64; ++i) r = 0.5 * (r + x / r);
  return r;
}
constexpr double su2cg(int j1, int m1, int j2, int m2, int j3, int m3) {
  if (m3 != m1 + m2) return 0.0;
  int vmin = -j1 + j2 + m3; if (-j1 + m1 > vmin) vmin = -j1 + m1; if (vmin < 0) vmin = 0;
  int vmax = j2 + j3 + m1; if (j3 - j1 + j2 < vmax) vmax = j3 - j1 + j2; if (j3 + m3 < vmax) vmax = j3 + m3;
  double C = csqrt((2.0 * j3 + 1.0)
                   * cfact(j3 + j1 - j2) * cfact(j3 - j1 + j2) * cfact(j1 + j2 - j3)
                   * cfact(j3 + m3) * cfact(j3 - m3)
                   / (cfact(j1 + j2 + j3 + 1) * cfact(j1 - m1) * cfact(j1 + m1)
                      * cfact(j2 - m2) * cfact(j2 + m2)));
  double S = 0.0;
  for (int v = vmin; v <= vmax; ++v) {
    double sgn = ((v + j2 + m2) & 1) ? -1.0 : 1.0;
    S += sgn * cfact(j2 + j3 + m1 - v) * cfact(j1 - m1 + v)
         / (cfact(v) * cfact(j3 - j1 + j2 - v) * cfact(j3 + m3 - v) * cfact(v + j1 - j2 - m3));
  }
  return C * S;
}

struct Cx { double re, im; };
constexpr Cx cxmul(Cx a, Cx b) { return Cx{a.re * b.re - a.im * b.im, a.re * b.im + a.im * b.re}; }
struct Row { int cnt; int col[2]; Cx v[2]; };

constexpr Row c2r_row(int l, int r) {
  Row out{0, {0, 0}, {{0, 0}, {0, 0}}};
  constexpr double is2 = 0.70710678118654752440;
  const int m = r - l;
  if (m < 0) {
    out.cnt = 2;
    out.col[0] = l - m; out.v[0] = Cx{is2, 0.0};
    out.col[1] = l + m; out.v[1] = Cx{0.0, -is2};
  } else if (m == 0) {
    out.cnt = 1; out.col[0] = l; out.v[0] = Cx{1.0, 0.0};
  } else {
    const double sgn = (m & 1) ? -1.0 : 1.0;
    out.cnt = 2;
    out.col[0] = l + m; out.v[0] = Cx{sgn * is2, 0.0};
    out.col[1] = l - m; out.v[1] = Cx{0.0, sgn * is2};
  }
  const int ph = l & 3;
  for (int a = 0; a < out.cnt; ++a) {
    Cx v = out.v[a];
    out.v[a] = (ph == 0) ? v
             : (ph == 1) ? Cx{v.im, -v.re}
             : (ph == 2) ? Cx{-v.re, -v.im}
                         : Cx{-v.im, v.re};
  }
  return out;
}

struct CGAll { float v[1105]; };
constexpr CGAll make_cg() {
  CGAll R{};
  for (int t = 0; t < 19; ++t) {
    const int l1 = T_L1c[t], l2 = T_L2c[t], l3 = T_L3c[t], off = T_OFFc[t];
    const int d1 = 2 * l1 + 1, d2 = 2 * l2 + 1, d3 = 2 * l3 + 1;
    double tmp[175] = {};
    for (int i = 0; i < d1; ++i) {
      const int m1 = i - l1;
      const Row r1 = c2r_row(l1, i);
      for (int k = 0; k < d2; ++k) {
        const int m2 = k - l2, m3 = m1 + m2;
        if (m3 < -l3 || m3 > l3) continue;
        const double cc = su2cg(l1, m1, l2, m2, l3, m3);
        if (cc == 0.0) continue;
        const Row r2 = c2r_row(l2, k);
        const Row r3 = c2r_row(l3, m3 + l3);
        for (int a = 0; a < r1.cnt; ++a)
          for (int b = 0; b < r2.cnt; ++b) {
            const Cx q12 = cxmul(r1.v[a], r2.v[b]);
            for (int cdx = 0; cdx < r3.cnt; ++cdx) {
              const double re = q12.re * r3.v[cdx].re + q12.im * r3.v[cdx].im;
              tmp[(r1.col[a] * d2 + r2.col[b]) * d3 + r3.col[cdx]] += re * cc;
            }
          }
      }
    }
    const int sz = d1 * d2 * d3;
    for (int e = 0; e < sz; ++e) R.v[off + e] = (float)tmp[e];
  }
  return R;
}
constexpr CGAll CG_ALL = make_cg();

constexpr bool check_cg_sym() {
  for (int t = 0; t < 18; ++t) {
    const int tc = TT_CANONc[t];
    if (tc == t) continue;
    const int l1 = K_L1c[t], l2 = K_L2c[t], l12 = K_L12c[t];
    const int d1 = 2*l1+1, d2 = 2*l2+1, d12 = 2*l12+1;
    for (int i = 0; i < d1; ++i)
      for (int j = 0; j < d2; ++j)
        for (int k = 0; k < d12; ++k) {
          float a = CG_ALL.v[T_OFFc[t]  + (i*d2 + j)*d12 + k];
          float b = TT_SGNc[t] * CG_ALL.v[T_OFFc[tc] + (j*d1 + i)*d12 + k];
          float d = a - b; if (d < 0) d = -d;
          if (d > 1e-5f) return false;
        }
  }
  return true;
}
static_assert(check_cg_sym(), "CG exchange symmetry violated");

// ============================ basis kernel (exact R9/R11 form) =================
__global__ __launch_bounds__(256) void epb_basis(
    const float* __restrict__ nf,      // [N, C, 9]
    const float* __restrict__ w1,      // [E, 2, C]
    const float* __restrict__ w2,      // [E, 9, C]
    const float* __restrict__ w3,      // [E, 51, C]
    const int*   __restrict__ species, // [N]
    float4* __restrict__ Bws)          // [N, C]
{
  const int t  = threadIdx.x;
  const int nb = blockIdx.x * 4;
  const int nl = t >> 6;               // wave-uniform node
  const int c0 = (t & 63) * 2;         // channel pair
  const int n  = nb + nl;
  const int s  = species[n];

  const float* ap = nf + ((size_t)n * NC + c0) * 9;
  v2f A[9];
  sfor<9>([&](auto I) { A[I.value] = v2f{ap[I.value], ap[I.value + 9]}; });

  const float* w1p = w1 + (size_t)s * 2  * NC + c0;
  const float* w2p = w2 + (size_t)s * 9  * NC + c0;
  const float* w3p = w3 + (size_t)s * 51 * NC + c0;

  v2f B[4];
  {
    const v2f wa = ld2(w1p), wb = ld2(w1p + NC);
    B[0] = wa * A[0];
    B[1] = wb * A[1];
    B[2] = wb * A[2];
    B[3] = wb * A[3];
  }

  sfor<7>([&](auto P) {
    constexpr int p  = P.value;
    constexpr int l1 = P2U_L1c[p], l2 = P2U_L2c[p], lo = P2U_LOc[p];
    constexpr int d1 = 2*l1+1, d2 = 2*l2+1, dl = 2*lo+1;
    constexpr int off = T_OFFc[P2U_TBLc[p]];
    v2f w = ld2(w2p + P2U_WAc[p] * NC);
    if constexpr (P2U_WBc[p] >= 0) w = w + ld2(w2p + P2U_WBc[p] * NC);
    sfor<dl>([&](auto Kk) {
      constexpr int k = Kk.value;
      v2f v = {0.f, 0.f};
      sfor<d1>([&](auto I) {
        sfor<d2>([&](auto J) {
          constexpr float cgc = CG_ALL.v[off + (I.value * d2 + J.value) * dl + k];
          if constexpr (cgc != 0.0f) {
            constexpr int ia = AOFFc[l1] + I.value, ja = AOFFc[l2] + J.value;
            constexpr int x = ia < ja ? ia : ja, y = ia < ja ? ja : ia;
            v = cfma(cgc, A[x] * A[y], v);
          }
        });
      });
      B[lo + k] = vfma(w, v, B[lo + k]);
    });
  });

  sfor<13>([&](auto CI) {
    constexpr int tk  = CANONc[CI.value];
    constexpr int l1  = K_L1c[tk], l2 = K_L2c[tk], l12 = K_L12c[tk];
    constexpr int d1  = 2*l1+1, d2 = 2*l2+1, d12 = 2*l12+1;
    constexpr int off = T_OFFc[tk];
    v2f tt[d12];
    sfor<d12>([&](auto Kk) {
      constexpr int k = Kk.value;
      v2f v = {0.f, 0.f};
      sfor<d1>([&](auto I) {
        sfor<d2>([&](auto J) {
          constexpr float cgc = CG_ALL.v[off + (I.value * d2 + J.value) * d12 + k];
          if constexpr (cgc != 0.0f) {
            constexpr int ia = AOFFc[l1] + I.value, ja = AOFFc[l2] + J.value;
            constexpr int x = ia < ja ? ia : ja, y = ia < ja ? ja : ia;
            v = cfma(cgc, A[x] * A[y], v);
          }
        });
      });
      tt[k] = v;
    });

    auto consume = [&](auto TK, auto SG) {
      constexpr int tkey = TK.value;
      constexpr float sgn = (float)SG.value;
      constexpr int pcnt = P3_STARTc[tkey + 1] - P3_STARTc[tkey];
      sfor<pcnt>([&](auto PP) {
        constexpr int p  = P3_STARTc[tkey] + PP.value;
        constexpr int l3 = P3_L3c[p], lo = P3_LOc[p];
        constexpr int d3 = 2*l3+1, dl = 2*lo+1;
        constexpr int off2 = T_OFFc[P3_TBLc[p]];
        const v2f w = ld2(w3p + p * NC);
        sfor<dl>([&](auto M) {
          v2f v = {0.f, 0.f};
          sfor<d12>([&](auto Kk) {
            sfor<d3>([&](auto J) {
              constexpr float cgc = sgn * CG_ALL.v[off2 + (Kk.value * d3 + J.value) * dl + M.value];
              if constexpr (cgc != 0.0f)
                v = cfma(cgc, tt[Kk.value] * A[AOFFc[l3] + J.value], v);
            });
          });
          B[lo + M.value] = vfma(w, v, B[lo + M.value]);
        });
      });
    };
    consume(std::integral_constant<int, tk>{}, std::integral_constant<int, 1>{});
    constexpr int td = CONS2c[CI.value];
    if constexpr (td >= 0)
      consume(std::integral_constant<int, td>{},
              std::integral_constant<int, (int)TT_SGNc[td]>{});
  });

  Bws[(size_t)n * NC + c0]     = make_float4(B[0].x, B[1].x, B[2].x, B[3].x);
  Bws[(size_t)n * NC + c0 + 1] = make_float4(B[0].y, B[1].y, B[2].y, B[3].y);
}

// ============================ linear kernel (GEMM-tiled) =======================
// 256 blocks x 256 thr; block owns 16 nodes x all 128 features.
// Thread = (fq = f-quad 0..31, ng = 0..7) -> 2 nodes (2ng, 2ng+1) x 4 f x
// 4 comps = 32 acc VGPR. 4 channel-chunks of 32: stage W0/W1 chunk (32KB)
// + B tile (8KB); inner c-loop: 2 spread b128 (W) + 2 broadcast b128 (B)
// per 32 FMA. Strided stores only at the tail.
__global__ __launch_bounds__(256) void epb_linear(
    const float4* __restrict__ Bws,    // [N, C]
    const float4* __restrict__ lw0_4,  // [C, F/4]
    const float4* __restrict__ lw1_4,  // [C, F/4]
    float* __restrict__ out)           // [N, F, 4]
{
  __shared__ float4 W0s[32 * 32];      // 16 KB  [c_local][f_quad]
  __shared__ float4 W1s[32 * 32];      // 16 KB
  __shared__ float4 Bt[LTN * 32];      //  8 KB  [node][c_local]

  const int t  = threadIdx.x;
  const int nb = blockIdx.x * LTN;
  const int fq = t & 31;
  const int ng = t >> 5;               // 0..7
  const int n0 = ng * 2;               // thread's first node (local)

  float4 acc[2][4] = {};               // [node][f_local], comps = m 0..3

  #pragma unroll 1
  for (int ph = 0; ph < 4; ++ph) {
    __syncthreads();                   // previous chunk fully consumed
    sfor<4>([&](auto K) {
      const int idx = t + 256 * K.value;
      W0s[idx] = lw0_4[ph * 1024 + idx];
      W1s[idx] = lw1_4[ph * 1024 + idx];
    });
    sfor<2>([&](auto K) {
      const int idx = t + 256 * K.value;           // node(4b) c(5b)
      Bt[idx] = Bws[(size_t)(nb + (idx >> 5)) * NC + ph * 32 + (idx & 31)];
    });
    __syncthreads();

    #pragma unroll 8
    for (int c = 0; c < 32; ++c) {
      const float4 wa = W0s[c * 32 + fq];   // 32 lanes x 16B consecutive
      const float4 wb = W1s[c * 32 + fq];
      const float4 b0 = Bt[n0 * 32 + c];    // broadcast (2 addrs/wave)
      const float4 b1 = Bt[(n0 + 1) * 32 + c];
#define FN(nn, b) \
      acc[nn][0].x = fmaf(b.x, wa.x, acc[nn][0].x); \
      acc[nn][0].y = fmaf(b.y, wb.x, acc[nn][0].y); \
      acc[nn][0].z = fmaf(b.z, wb.x, acc[nn][0].z); \
      acc[nn][0].w = fmaf(b.w, wb.x, acc[nn][0].w); \
      acc[nn][1].x = fmaf(b.x, wa.y, acc[nn][1].x); \
      acc[nn][1].y = fmaf(b.y, wb.y, acc[nn][1].y); \
      acc[nn][1].z = fmaf(b.z, wb.y, acc[nn][1].z); \
      acc[nn][1].w = fmaf(b.w, wb.y, acc[nn][1].w); \
      acc[nn][2].x = fmaf(b.x, wa.z, acc[nn][2].x); \
      acc[nn][2].y = fmaf(b.y, wb.z, acc[nn][2].y); \
      acc[nn][2].z = fmaf(b.z, wb.z, acc[nn][2].z); \
      acc[nn][2].w = fmaf(b.w, wb.z, acc[nn][2].w); \
      acc[nn][3].x = fmaf(b.x, wa.w, acc[nn][3].x); \
      acc[nn][3].y = fmaf(b.y, wb.w, acc[nn][3].y); \
      acc[nn][3].z = fmaf(b.z, wb.w, acc[nn][3].z); \
      acc[nn][3].w = fmaf(b.w, wb.w, acc[nn][3].w);
      FN(0, b0)
      FN(1, b1)
#undef FN
    }
  }

  const float s4 = 0.08838834764831845f;  // 1/sqrt(128)
  float4* o4 = reinterpret_cast<float4*>(out);
  sfor<2>([&](auto NN_) {
    sfor<4>([&](auto F_) {
      const float4 a = acc[NN_.value][F_.value];
      o4[(size_t)(nb + n0 + NN_.value) * NC + 4 * fq + F_.value] =
          make_float4(a.x * s4, a.y * s4, a.z * s4, a.w * s4);
    });
  });
}

// ------------------------------- launcher --------------------------------------
extern "C" void kernel_launch(void* const* d_in, const int* in_sizes, int n_in,
                              void* d_out, int out_size, void* d_ws, size_t ws_size,
                              hipStream_t stream) {
  const float* nf  = (const float*)d_in[0];
  const float* w1  = (const float*)d_in[1];
  const float* w2  = (const float*)d_in[2];
  const float* w3  = (const float*)d_in[3];
  const float* lw0 = (const float*)d_in[4];
  const float* lw1 = (const float*)d_in[5];
  const int*   spc = (const int*)  d_in[6];
  float* out = (float*)d_out;
  float4* Bws = (float4*)d_ws;   // [N][C] float4 = 8 MB
  (void)ws_size; (void)in_sizes; (void)n_in; (void)out_size;

  hipLaunchKernelGGL(epb_basis, dim3(NN / 4), dim3(256), 0, stream,
                     nf, w1, w2, w3, spc, Bws);
  hipLaunchKernelGGL(epb_linear, dim3(NN / LTN), dim3(256), 0, stream,
                     Bws, (const float4*)lw0, (const float4*)lw1, out);
}